// Round 1
// baseline (995.902 us; speedup 1.0000x reference)
//
#include <hip/hip_runtime.h>
#include <hip/hip_bf16.h>

// B=128, S=1024, F=512, H=32, G=128. rows = B*S = 131072.
// Pipeline: k1: x->xg (3 fused GEMMs, bf16 MFMA, x split hi/lo for precision)
//           k2: LSTM scan (fp32, 1 wave per batch, shuffle-based, no barriers)
//           k3: hs->out (2 fused GEMMs, bf16 MFMA)

typedef __attribute__((ext_vector_type(8))) __bf16 bf16x8;
typedef __attribute__((ext_vector_type(4))) __bf16 bf16x4;
typedef __attribute__((ext_vector_type(4))) float floatx4;

// ---------------------------------------------------------------- kernel 1
// 64 rows/block, 4 waves (16 rows each). LDS carve (51712 B):
//  region A: [0)      w1T[32][520] (33280B)  -> later w2T[64][40]@0 + wxT[128][72]@5120
//  region B: [33280)  xsh[64][72] + xsl[64][72]@42496 -> later h1s[64][40]@33280 + h2s[64][72]@38400
__global__ __launch_bounds__(256) void k_mlp_xg(
    const float* __restrict__ x,  const float* __restrict__ W1, const float* __restrict__ b1,
    const float* __restrict__ W2, const float* __restrict__ b2,
    const float* __restrict__ Wx, const float* __restrict__ bl,
    float* __restrict__ xg)
{
    __shared__ __align__(16) char smem[51712];
    __bf16* w1T = (__bf16*)smem;             // [32][520]
    __bf16* w2T = (__bf16*)smem;             // [64][40]
    __bf16* wxT = (__bf16*)(smem + 5120);    // [128][72]
    __bf16* xsh = (__bf16*)(smem + 33280);   // [64][72]  (K-chunk of 64)
    __bf16* xsl = (__bf16*)(smem + 42496);   // [64][72]
    __bf16* h1s = (__bf16*)(smem + 33280);   // [64][40]
    __bf16* h2s = (__bf16*)(smem + 38400);   // [64][72]

    const int tid  = threadIdx.x;
    const int lane = tid & 63, w = tid >> 6;
    const int quad = lane >> 4, col = lane & 15;
    const int row0 = blockIdx.x * 64;
    const int m     = w * 16 + col;          // A-frag row (block-local)
    const int rbase = w * 16 + quad * 4;     // C-frag row base (block-local)
    const floatx4 fzero = {0.f, 0.f, 0.f, 0.f};

    // stage W1^T as bf16 (once; whole K=512)
    for (int i = tid; i < 512 * 32; i += 256) {
        int k = i >> 5, n = i & 31;
        w1T[n * 520 + k] = (__bf16)W1[i];
    }
    auto stage_x = [&](int kc) {
        for (int i4 = tid; i4 < 1024; i4 += 256) {
            int f = i4 << 2; int r = f >> 6, cc = f & 63;
            float4 v = *(const float4*)(x + (size_t)(row0 + r) * 512 + kc * 64 + cc);
            __bf16 h0 = (__bf16)v.x, h1 = (__bf16)v.y, h2 = (__bf16)v.z, h3 = (__bf16)v.w;
            bf16x4 hi = {h0, h1, h2, h3};
            bf16x4 lo = {(__bf16)(v.x - (float)h0), (__bf16)(v.y - (float)h1),
                         (__bf16)(v.z - (float)h2), (__bf16)(v.w - (float)h3)};
            *(bf16x4*)(xsh + r * 72 + cc) = hi;
            *(bf16x4*)(xsl + r * 72 + cc) = lo;
        }
    };
    stage_x(0);
    __syncthreads();

    // ---- layer1: h1 = tanh(x @ W1 + b1), K=512 (8 chunks of 64), N=32 (2 tiles)
    floatx4 acc1[2] = {fzero, fzero};
    for (int kc = 0; kc < 8; ++kc) {
#pragma unroll
        for (int ks = 0; ks < 2; ++ks) {
            int ko = ks * 32 + quad * 8;
            bf16x8 ah = *(const bf16x8*)(xsh + m * 72 + ko);
            bf16x8 al = *(const bf16x8*)(xsl + m * 72 + ko);
            int kg = kc * 64 + ko;
#pragma unroll
            for (int nt = 0; nt < 2; ++nt) {
                bf16x8 bfr = *(const bf16x8*)(w1T + (nt * 16 + col) * 520 + kg);
                acc1[nt] = __builtin_amdgcn_mfma_f32_16x16x32_bf16(ah, bfr, acc1[nt], 0, 0, 0);
                acc1[nt] = __builtin_amdgcn_mfma_f32_16x16x32_bf16(al, bfr, acc1[nt], 0, 0, 0);
            }
        }
        if (kc < 7) { __syncthreads(); stage_x(kc + 1); __syncthreads(); }
    }
    __syncthreads();   // all waves done reading xs / w1T

#pragma unroll
    for (int nt = 0; nt < 2; ++nt) {
        float bb = b1[nt * 16 + col];
#pragma unroll
        for (int r = 0; r < 4; ++r)
            h1s[(rbase + r) * 40 + nt * 16 + col] = (__bf16)tanhf(acc1[nt][r] + bb);
    }
    // stage W2^T and Wx^T (region A, w1T dead)
    for (int i = tid; i < 32 * 64; i += 256)  { int k = i >> 6, n = i & 63;  w2T[n * 40 + k] = (__bf16)W2[i]; }
    for (int i = tid; i < 64 * 128; i += 256) { int k = i >> 7, n = i & 127; wxT[n * 72 + k] = (__bf16)Wx[i]; }
    __syncthreads();

    // ---- layer2: h2 = tanh(h1 @ W2 + b2), K=32, N=64 (4 tiles)
    bf16x8 a2 = *(const bf16x8*)(h1s + m * 40 + quad * 8);
    floatx4 acc2[4];
#pragma unroll
    for (int nt = 0; nt < 4; ++nt) {
        bf16x8 bfr = *(const bf16x8*)(w2T + (nt * 16 + col) * 40 + quad * 8);
        acc2[nt] = __builtin_amdgcn_mfma_f32_16x16x32_bf16(a2, bfr, fzero, 0, 0, 0);
    }
#pragma unroll
    for (int nt = 0; nt < 4; ++nt) {
        float bb = b2[nt * 16 + col];
#pragma unroll
        for (int r = 0; r < 4; ++r)
            h2s[(rbase + r) * 72 + nt * 16 + col] = (__bf16)tanhf(acc2[nt][r] + bb);
    }
    // no barrier: each wave reads only its own 16 rows of h2s

    // ---- layer3: xg = h2 @ Wx + bl, K=64 (2 steps), N=128 (8 tiles)
    floatx4 acc3[8];
#pragma unroll
    for (int nt = 0; nt < 8; ++nt) acc3[nt] = fzero;
#pragma unroll
    for (int ks = 0; ks < 2; ++ks) {
        int ko = ks * 32 + quad * 8;
        bf16x8 a3 = *(const bf16x8*)(h2s + m * 72 + ko);
#pragma unroll
        for (int nt = 0; nt < 8; ++nt) {
            bf16x8 bfr = *(const bf16x8*)(wxT + (nt * 16 + col) * 72 + ko);
            acc3[nt] = __builtin_amdgcn_mfma_f32_16x16x32_bf16(a3, bfr, acc3[nt], 0, 0, 0);
        }
    }
#pragma unroll
    for (int nt = 0; nt < 8; ++nt) {
        float bb = bl[nt * 16 + col];
#pragma unroll
        for (int r = 0; r < 4; ++r)
            xg[(size_t)(row0 + rbase + r) * 128 + nt * 16 + col] = acc3[nt][r] + bb;
    }
}

// ---------------------------------------------------------------- kernel 2
// One wave per batch. Lane l owns gates l and l+64 (Wh columns in 64 VGPRs).
// h_j lives in lane j (j<32). Gate order: [i(0:32) f(32:64) g(64:96) o(96:128)].
__global__ __launch_bounds__(64) void k_lstm(
    const float* __restrict__ xg, const float* __restrict__ Wh,
    float* __restrict__ hs)
{
    const int b = blockIdx.x;
    const int l = threadIdx.x;
    const float* xgb = xg + (size_t)b * 1024 * 128;
    float* hsb = hs + (size_t)b * 1024 * 32;

    float whA[32], whB[32];
#pragma unroll
    for (int k = 0; k < 32; ++k) {
        whA[k] = Wh[k * 128 + l];        // column for gate l
        whB[k] = Wh[k * 128 + 64 + l];   // column for gate l+64
    }
    const float sc1 = (l < 32) ? 2.0f : 1.0f;   // tanh(x)=2*sigmoid(2x)-1 trick
    float c = 0.f, h = 0.f;
    float x0 = xgb[l], x1 = xgb[64 + l];

    for (int t = 0; t < 1024; ++t) {
        float nx0 = 0.f, nx1 = 0.f;              // prefetch next step's xg
        if (t < 1023) { nx0 = xgb[(t + 1) * 128 + l]; nx1 = xgb[(t + 1) * 128 + 64 + l]; }
        float p0a = x0, p0b = 0.f, p0c = 0.f, p0d = 0.f;
        float p1a = x1, p1b = 0.f, p1c = 0.f, p1d = 0.f;
#pragma unroll
        for (int k = 0; k < 32; k += 4) {
            float h0 = __shfl(h, k);
            float h1 = __shfl(h, k + 1);
            float h2 = __shfl(h, k + 2);
            float h3 = __shfl(h, k + 3);
            p0a += h0 * whA[k];     p1a += h0 * whB[k];
            p0b += h1 * whA[k + 1]; p1b += h1 * whB[k + 1];
            p0c += h2 * whA[k + 2]; p1c += h2 * whB[k + 2];
            p0d += h3 * whA[k + 3]; p1d += h3 * whB[k + 3];
        }
        float pre0 = (p0a + p0b) + (p0c + p0d);  // i (l<32) / f (l>=32)
        float pre1 = (p1a + p1b) + (p1c + p1d);  // g (l<32) / o (l>=32)
        float a0 = 1.0f / (1.0f + __expf(-pre0));            // sigmoid(i|f)
        float s1 = 1.0f / (1.0f + __expf(-sc1 * pre1));
        float a1 = (l < 32) ? (2.0f * s1 - 1.0f) : s1;       // tanh(g) | sigmoid(o)
        float f_ = __shfl(a0, l ^ 32);   // lane j<32 gets f_j
        float o_ = __shfl(a1, l ^ 32);   // lane j<32 gets o_j
        c = f_ * c + a0 * a1;            // valid in lanes 0-31 (upper lanes: garbage, never read)
        float e = __expf(-2.0f * c);
        float th = (1.0f - e) / (1.0f + e);
        h = o_ * th;
        if (l < 32) hsb[t * 32 + l] = h;
        x0 = nx0; x1 = nx1;
    }
}

// ---------------------------------------------------------------- kernel 3
// 64 rows/block. LDS: hss[64][40]@0, w3T[64][40]@5120, h3s[64][72]@10240,
//                     w4T[128][72]@19456  (total 37888 B)
__global__ __launch_bounds__(256) void k_tail(
    const float* __restrict__ hs, const float* __restrict__ W3, const float* __restrict__ b3,
    const float* __restrict__ W4, const float* __restrict__ b4,
    float* __restrict__ out)
{
    __shared__ __align__(16) char smem[37888];
    __bf16* hss = (__bf16*)smem;
    __bf16* w3T = (__bf16*)(smem + 5120);
    __bf16* h3s = (__bf16*)(smem + 10240);
    __bf16* w4T = (__bf16*)(smem + 19456);

    const int tid  = threadIdx.x;
    const int lane = tid & 63, w = tid >> 6;
    const int quad = lane >> 4, col = lane & 15;
    const int row0 = blockIdx.x * 64;
    const int m     = w * 16 + col;
    const int rbase = w * 16 + quad * 4;
    const floatx4 fzero = {0.f, 0.f, 0.f, 0.f};

    for (int i4 = tid; i4 < 512; i4 += 256) {
        int f = i4 << 2; int r = f >> 5, cc = f & 31;
        float4 v = *(const float4*)(hs + (size_t)(row0 + r) * 32 + cc);
        bf16x4 hv = {(__bf16)v.x, (__bf16)v.y, (__bf16)v.z, (__bf16)v.w};
        *(bf16x4*)(hss + r * 40 + cc) = hv;
    }
    for (int i = tid; i < 32 * 64; i += 256) { int k = i >> 6, n = i & 63; w3T[n * 40 + k] = (__bf16)W3[i]; }
    __syncthreads();

    // ---- h3 = tanh(hs @ W3 + b3), K=32, N=64
    bf16x8 a3 = *(const bf16x8*)(hss + m * 40 + quad * 8);
    floatx4 acc3[4];
#pragma unroll
    for (int nt = 0; nt < 4; ++nt) {
        bf16x8 bfr = *(const bf16x8*)(w3T + (nt * 16 + col) * 40 + quad * 8);
        acc3[nt] = __builtin_amdgcn_mfma_f32_16x16x32_bf16(a3, bfr, fzero, 0, 0, 0);
    }
#pragma unroll
    for (int nt = 0; nt < 4; ++nt) {
        float bb = b3[nt * 16 + col];
#pragma unroll
        for (int r = 0; r < 4; ++r)
            h3s[(rbase + r) * 72 + nt * 16 + col] = (__bf16)tanhf(acc3[nt][r] + bb);
    }

    // ---- out = h3 @ W4 + b4, K=64, N=512 in 4 column chunks of 128
    for (int oc = 0; oc < 4; ++oc) {
        __syncthreads();   // prior chunk's B-frag reads done before w4T rewrite
        for (int i4 = tid; i4 < 2048; i4 += 256) {
            int f = i4 << 2; int k = f >> 7, cc = f & 127;
            float4 v = *(const float4*)(W4 + (size_t)k * 512 + oc * 128 + cc);
            w4T[(cc + 0) * 72 + k] = (__bf16)v.x;
            w4T[(cc + 1) * 72 + k] = (__bf16)v.y;
            w4T[(cc + 2) * 72 + k] = (__bf16)v.z;
            w4T[(cc + 3) * 72 + k] = (__bf16)v.w;
        }
        __syncthreads();

        floatx4 acc4[8];
#pragma unroll
        for (int nt = 0; nt < 8; ++nt) acc4[nt] = fzero;
#pragma unroll
        for (int ks = 0; ks < 2; ++ks) {
            int ko = ks * 32 + quad * 8;
            bf16x8 a4 = *(const bf16x8*)(h3s + m * 72 + ko);
#pragma unroll
            for (int nt = 0; nt < 8; ++nt) {
                bf16x8 bfr = *(const bf16x8*)(w4T + (nt * 16 + col) * 72 + ko);
                acc4[nt] = __builtin_amdgcn_mfma_f32_16x16x32_bf16(a4, bfr, acc4[nt], 0, 0, 0);
            }
        }
#pragma unroll
        for (int nt = 0; nt < 8; ++nt) {
            float bb = b4[oc * 128 + nt * 16 + col];
#pragma unroll
            for (int r = 0; r < 4; ++r)
                out[(size_t)(row0 + rbase + r) * 512 + oc * 128 + nt * 16 + col] = acc4[nt][r] + bb;
        }
    }
}

// ---------------------------------------------------------------- launch
extern "C" void kernel_launch(void* const* d_in, const int* in_sizes, int n_in,
                              void* d_out, int out_size, void* d_ws, size_t ws_size,
                              hipStream_t stream)
{
    (void)in_sizes; (void)n_in; (void)out_size;
    const float* x  = (const float*)d_in[0];
    const float* W1 = (const float*)d_in[1];
    const float* b1 = (const float*)d_in[2];
    const float* W2 = (const float*)d_in[3];
    const float* b2 = (const float*)d_in[4];
    const float* Wx = (const float*)d_in[5];
    const float* Wh = (const float*)d_in[6];
    const float* bl = (const float*)d_in[7];
    const float* W3 = (const float*)d_in[8];
    const float* b3 = (const float*)d_in[9];
    const float* W4 = (const float*)d_in[10];
    const float* b4 = (const float*)d_in[11];
    float* out = (float*)d_out;

    const size_t hsElems = (size_t)128 * 1024 * 32;    // 16 MB
    const size_t xgElems = (size_t)128 * 1024 * 128;   // 64 MB
    float* hs = (float*)d_ws;
    float* xg = (ws_size >= (hsElems + xgElems) * sizeof(float))
                    ? hs + hsElems
                    : out;   // stash xg in d_out; k3 rewrites d_out only after hs is done

    k_mlp_xg<<<2048, 256, 0, stream>>>(x, W1, b1, W2, b2, Wx, bl, xg);
    k_lstm<<<128, 64, 0, stream>>>(xg, Wh, hs);
    k_tail<<<2048, 256, 0, stream>>>(hs, W3, b3, W4, b4, out);
}

// Round 2
// 880.246 us; speedup vs baseline: 1.1314x; 1.1314x over previous
//
#include <hip/hip_runtime.h>
#include <hip/hip_bf16.h>

// B=128, S=1024, F=512, H=32, G=128. rows = B*S = 131072.
// Pipeline: k1: x->xg (3 fused GEMMs, bf16 MFMA, x split hi/lo for precision)
//           k2: LSTM scan (fp32, 1 wave per batch, readlane matvec, 4-deep prefetch)
//           k3: hs->out (2 fused GEMMs, bf16 MFMA)

typedef __attribute__((ext_vector_type(8))) __bf16 bf16x8;
typedef __attribute__((ext_vector_type(4))) __bf16 bf16x4;
typedef __attribute__((ext_vector_type(4))) float floatx4;

// ---------------------------------------------------------------- kernel 1
// 64 rows/block, 4 waves (16 rows each). LDS carve (51712 B):
//  region A: [0)      w1T[32][520] (33280B)  -> later w2T[64][40]@0 + wxT[128][72]@5120
//  region B: [33280)  xsh[64][72] + xsl[64][72]@42496 -> later h1s[64][40]@33280 + h2s[64][72]@38400
__global__ __launch_bounds__(256) void k_mlp_xg(
    const float* __restrict__ x,  const float* __restrict__ W1, const float* __restrict__ b1,
    const float* __restrict__ W2, const float* __restrict__ b2,
    const float* __restrict__ Wx, const float* __restrict__ bl,
    float* __restrict__ xg)
{
    __shared__ __align__(16) char smem[51712];
    __bf16* w1T = (__bf16*)smem;             // [32][520]
    __bf16* w2T = (__bf16*)smem;             // [64][40]
    __bf16* wxT = (__bf16*)(smem + 5120);    // [128][72]
    __bf16* xsh = (__bf16*)(smem + 33280);   // [64][72]  (K-chunk of 64)
    __bf16* xsl = (__bf16*)(smem + 42496);   // [64][72]
    __bf16* h1s = (__bf16*)(smem + 33280);   // [64][40]
    __bf16* h2s = (__bf16*)(smem + 38400);   // [64][72]

    const int tid  = threadIdx.x;
    const int lane = tid & 63, w = tid >> 6;
    const int quad = lane >> 4, col = lane & 15;
    const int row0 = blockIdx.x * 64;
    const int m     = w * 16 + col;          // A-frag row (block-local)
    const int rbase = w * 16 + quad * 4;     // C-frag row base (block-local)
    const floatx4 fzero = {0.f, 0.f, 0.f, 0.f};

    // stage W1^T as bf16 (once; whole K=512)
    for (int i = tid; i < 512 * 32; i += 256) {
        int k = i >> 5, n = i & 31;
        w1T[n * 520 + k] = (__bf16)W1[i];
    }
    auto stage_x = [&](int kc) {
        for (int i4 = tid; i4 < 1024; i4 += 256) {
            int f = i4 << 2; int r = f >> 6, cc = f & 63;
            float4 v = *(const float4*)(x + (size_t)(row0 + r) * 512 + kc * 64 + cc);
            __bf16 h0 = (__bf16)v.x, h1 = (__bf16)v.y, h2 = (__bf16)v.z, h3 = (__bf16)v.w;
            bf16x4 hi = {h0, h1, h2, h3};
            bf16x4 lo = {(__bf16)(v.x - (float)h0), (__bf16)(v.y - (float)h1),
                         (__bf16)(v.z - (float)h2), (__bf16)(v.w - (float)h3)};
            *(bf16x4*)(xsh + r * 72 + cc) = hi;
            *(bf16x4*)(xsl + r * 72 + cc) = lo;
        }
    };
    stage_x(0);
    __syncthreads();

    // ---- layer1: h1 = tanh(x @ W1 + b1), K=512 (8 chunks of 64), N=32 (2 tiles)
    floatx4 acc1[2] = {fzero, fzero};
    for (int kc = 0; kc < 8; ++kc) {
#pragma unroll
        for (int ks = 0; ks < 2; ++ks) {
            int ko = ks * 32 + quad * 8;
            bf16x8 ah = *(const bf16x8*)(xsh + m * 72 + ko);
            bf16x8 al = *(const bf16x8*)(xsl + m * 72 + ko);
            int kg = kc * 64 + ko;
#pragma unroll
            for (int nt = 0; nt < 2; ++nt) {
                bf16x8 bfr = *(const bf16x8*)(w1T + (nt * 16 + col) * 520 + kg);
                acc1[nt] = __builtin_amdgcn_mfma_f32_16x16x32_bf16(ah, bfr, acc1[nt], 0, 0, 0);
                acc1[nt] = __builtin_amdgcn_mfma_f32_16x16x32_bf16(al, bfr, acc1[nt], 0, 0, 0);
            }
        }
        if (kc < 7) { __syncthreads(); stage_x(kc + 1); __syncthreads(); }
    }
    __syncthreads();   // all waves done reading xs / w1T

#pragma unroll
    for (int nt = 0; nt < 2; ++nt) {
        float bb = b1[nt * 16 + col];
#pragma unroll
        for (int r = 0; r < 4; ++r)
            h1s[(rbase + r) * 40 + nt * 16 + col] = (__bf16)tanhf(acc1[nt][r] + bb);
    }
    // stage W2^T and Wx^T (region A, w1T dead)
    for (int i = tid; i < 32 * 64; i += 256)  { int k = i >> 6, n = i & 63;  w2T[n * 40 + k] = (__bf16)W2[i]; }
    for (int i = tid; i < 64 * 128; i += 256) { int k = i >> 7, n = i & 127; wxT[n * 72 + k] = (__bf16)Wx[i]; }
    __syncthreads();

    // ---- layer2: h2 = tanh(h1 @ W2 + b2), K=32, N=64 (4 tiles)
    bf16x8 a2 = *(const bf16x8*)(h1s + m * 40 + quad * 8);
    floatx4 acc2[4];
#pragma unroll
    for (int nt = 0; nt < 4; ++nt) {
        bf16x8 bfr = *(const bf16x8*)(w2T + (nt * 16 + col) * 40 + quad * 8);
        acc2[nt] = __builtin_amdgcn_mfma_f32_16x16x32_bf16(a2, bfr, fzero, 0, 0, 0);
    }
#pragma unroll
    for (int nt = 0; nt < 4; ++nt) {
        float bb = b2[nt * 16 + col];
#pragma unroll
        for (int r = 0; r < 4; ++r)
            h2s[(rbase + r) * 72 + nt * 16 + col] = (__bf16)tanhf(acc2[nt][r] + bb);
    }
    // no barrier: each wave reads only its own 16 rows of h2s

    // ---- layer3: xg = h2 @ Wx + bl, K=64 (2 steps), N=128 (8 tiles)
    floatx4 acc3[8];
#pragma unroll
    for (int nt = 0; nt < 8; ++nt) acc3[nt] = fzero;
#pragma unroll
    for (int ks = 0; ks < 2; ++ks) {
        int ko = ks * 32 + quad * 8;
        bf16x8 a3 = *(const bf16x8*)(h2s + m * 72 + ko);
#pragma unroll
        for (int nt = 0; nt < 8; ++nt) {
            bf16x8 bfr = *(const bf16x8*)(wxT + (nt * 16 + col) * 72 + ko);
            acc3[nt] = __builtin_amdgcn_mfma_f32_16x16x32_bf16(a3, bfr, acc3[nt], 0, 0, 0);
        }
    }
#pragma unroll
    for (int nt = 0; nt < 8; ++nt) {
        float bb = bl[nt * 16 + col];
#pragma unroll
        for (int r = 0; r < 4; ++r)
            xg[(size_t)(row0 + rbase + r) * 128 + nt * 16 + col] = acc3[nt][r] + bb;
    }
}

// ---------------------------------------------------------------- kernel 2
// One wave per batch (128 blocks x 64 threads). Lane l owns gates l and l+64
// (Wh columns in 64 VGPRs). h_j lives in lane j (j<32).
// Gate order: [i(0:32) f(32:64) g(64:96) o(96:128)].
//
// R2 changes vs R1 (latency-bound, 1064 cyc/step measured):
//  - 4-deep register prefetch ring for xg (hides ~900-cyc HBM latency; depth-1
//    ring exposed ~700 cyc/step).
//  - h broadcast via v_readlane -> SGPR feeding v_fmac (s,v) directly, off the
//    LDS/bpermute pipe.
//  - sigmoid/tanh via v_rcp instead of full-precision fp32 divide sequence.
#define RLANE(v, k) __uint_as_float(__builtin_amdgcn_readlane(__float_as_uint(v), (k)))

__global__ __launch_bounds__(64) void k_lstm(
    const float* __restrict__ xg, const float* __restrict__ Wh,
    float* __restrict__ hs)
{
    const int b = blockIdx.x;
    const int l = threadIdx.x;
    const float* xgb = xg + (size_t)b * 1024 * 128;
    float* hsb = hs + (size_t)b * 1024 * 32;

    float whA[32], whB[32];
#pragma unroll
    for (int k = 0; k < 32; ++k) {
        whA[k] = Wh[k * 128 + l];        // column for gate l
        whB[k] = Wh[k * 128 + 64 + l];   // column for gate l+64
    }
    // a1 = (l<32) ? 2*s1-1 : s1  done branch-free: a1 = s1*m1 + c1
    const float sc1 = (l < 32) ? 2.0f : 1.0f;    // tanh(x)=2*sigmoid(2x)-1
    const float m1  = (l < 32) ? 2.0f : 1.0f;
    const float c1  = (l < 32) ? -1.0f : 0.0f;

    float c = 0.f, h = 0.f;

    // prefetch ring, depth 4
    float xr0[4], xr1[4];
#pragma unroll
    for (int p = 0; p < 4; ++p) {
        xr0[p] = xgb[p * 128 + l];
        xr1[p] = xgb[p * 128 + 64 + l];
    }

    for (int t = 0; t < 1024; t += 4) {
#pragma unroll
        for (int u = 0; u < 4; ++u) {
            const int tc = t + u;
            float x0 = xr0[u], x1 = xr1[u];
            // issue prefetch for step tc+4 (clamped; tail re-reads step 1023, L2-hot)
            {
                int tp = tc + 4; tp = (tp > 1023) ? 1023 : tp;
                xr0[u] = xgb[tp * 128 + l];
                xr1[u] = xgb[tp * 128 + 64 + l];
            }
            float p0a = x0, p0b = 0.f, p0c = 0.f, p0d = 0.f;
            float p1a = x1, p1b = 0.f, p1c = 0.f, p1d = 0.f;
#pragma unroll
            for (int k = 0; k < 32; k += 4) {
                float h0 = RLANE(h, k);
                float h1 = RLANE(h, k + 1);
                float h2 = RLANE(h, k + 2);
                float h3 = RLANE(h, k + 3);
                p0a += h0 * whA[k];     p1a += h0 * whB[k];
                p0b += h1 * whA[k + 1]; p1b += h1 * whB[k + 1];
                p0c += h2 * whA[k + 2]; p1c += h2 * whB[k + 2];
                p0d += h3 * whA[k + 3]; p1d += h3 * whB[k + 3];
            }
            float pre0 = (p0a + p0b) + (p0c + p0d);  // i (l<32) / f (l>=32)
            float pre1 = (p1a + p1b) + (p1c + p1d);  // g (l<32) / o (l>=32)
            float a0 = __builtin_amdgcn_rcpf(1.0f + __expf(-pre0));       // sigmoid(i|f)
            float s1 = __builtin_amdgcn_rcpf(1.0f + __expf(-sc1 * pre1));
            float a1 = __builtin_fmaf(s1, m1, c1);                        // tanh(g) | sigmoid(o)
            float f_ = __shfl(a0, l ^ 32);   // lane j<32 gets f_j
            float o_ = __shfl(a1, l ^ 32);   // lane j<32 gets o_j
            c = f_ * c + a0 * a1;            // valid in lanes 0-31 (upper: garbage, never read)
            float e = __expf(-2.0f * c);
            float th = (1.0f - e) * __builtin_amdgcn_rcpf(1.0f + e);
            h = o_ * th;
            if (l < 32) hsb[tc * 32 + l] = h;
        }
    }
}

// ---------------------------------------------------------------- kernel 3
// 64 rows/block. LDS: hss[64][40]@0, w3T[64][40]@5120, h3s[64][72]@10240,
//                     w4T[128][72]@19456  (total 37888 B)
__global__ __launch_bounds__(256) void k_tail(
    const float* __restrict__ hs, const float* __restrict__ W3, const float* __restrict__ b3,
    const float* __restrict__ W4, const float* __restrict__ b4,
    float* __restrict__ out)
{
    __shared__ __align__(16) char smem[37888];
    __bf16* hss = (__bf16*)smem;
    __bf16* w3T = (__bf16*)(smem + 5120);
    __bf16* h3s = (__bf16*)(smem + 10240);
    __bf16* w4T = (__bf16*)(smem + 19456);

    const int tid  = threadIdx.x;
    const int lane = tid & 63, w = tid >> 6;
    const int quad = lane >> 4, col = lane & 15;
    const int row0 = blockIdx.x * 64;
    const int m     = w * 16 + col;
    const int rbase = w * 16 + quad * 4;
    const floatx4 fzero = {0.f, 0.f, 0.f, 0.f};

    for (int i4 = tid; i4 < 512; i4 += 256) {
        int f = i4 << 2; int r = f >> 5, cc = f & 31;
        float4 v = *(const float4*)(hs + (size_t)(row0 + r) * 32 + cc);
        bf16x4 hv = {(__bf16)v.x, (__bf16)v.y, (__bf16)v.z, (__bf16)v.w};
        *(bf16x4*)(hss + r * 40 + cc) = hv;
    }
    for (int i = tid; i < 32 * 64; i += 256) { int k = i >> 6, n = i & 63; w3T[n * 40 + k] = (__bf16)W3[i]; }
    __syncthreads();

    // ---- h3 = tanh(hs @ W3 + b3), K=32, N=64
    bf16x8 a3 = *(const bf16x8*)(hss + m * 40 + quad * 8);
    floatx4 acc3[4];
#pragma unroll
    for (int nt = 0; nt < 4; ++nt) {
        bf16x8 bfr = *(const bf16x8*)(w3T + (nt * 16 + col) * 40 + quad * 8);
        acc3[nt] = __builtin_amdgcn_mfma_f32_16x16x32_bf16(a3, bfr, fzero, 0, 0, 0);
    }
#pragma unroll
    for (int nt = 0; nt < 4; ++nt) {
        float bb = b3[nt * 16 + col];
#pragma unroll
        for (int r = 0; r < 4; ++r)
            h3s[(rbase + r) * 72 + nt * 16 + col] = (__bf16)tanhf(acc3[nt][r] + bb);
    }

    // ---- out = h3 @ W4 + b4, K=64, N=512 in 4 column chunks of 128
    for (int oc = 0; oc < 4; ++oc) {
        __syncthreads();   // prior chunk's B-frag reads done before w4T rewrite
        for (int i4 = tid; i4 < 2048; i4 += 256) {
            int f = i4 << 2; int k = f >> 7, cc = f & 127;
            float4 v = *(const float4*)(W4 + (size_t)k * 512 + oc * 128 + cc);
            w4T[(cc + 0) * 72 + k] = (__bf16)v.x;
            w4T[(cc + 1) * 72 + k] = (__bf16)v.y;
            w4T[(cc + 2) * 72 + k] = (__bf16)v.z;
            w4T[(cc + 3) * 72 + k] = (__bf16)v.w;
        }
        __syncthreads();

        floatx4 acc4[8];
#pragma unroll
        for (int nt = 0; nt < 8; ++nt) acc4[nt] = fzero;
#pragma unroll
        for (int ks = 0; ks < 2; ++ks) {
            int ko = ks * 32 + quad * 8;
            bf16x8 a4 = *(const bf16x8*)(h3s + m * 72 + ko);
#pragma unroll
            for (int nt = 0; nt < 8; ++nt) {
                bf16x8 bfr = *(const bf16x8*)(w4T + (nt * 16 + col) * 72 + ko);
                acc4[nt] = __builtin_amdgcn_mfma_f32_16x16x32_bf16(a4, bfr, acc4[nt], 0, 0, 0);
            }
        }
#pragma unroll
        for (int nt = 0; nt < 8; ++nt) {
            float bb = b4[oc * 128 + nt * 16 + col];
#pragma unroll
            for (int r = 0; r < 4; ++r)
                out[(size_t)(row0 + rbase + r) * 512 + oc * 128 + nt * 16 + col] = acc4[nt][r] + bb;
        }
    }
}

// ---------------------------------------------------------------- launch
extern "C" void kernel_launch(void* const* d_in, const int* in_sizes, int n_in,
                              void* d_out, int out_size, void* d_ws, size_t ws_size,
                              hipStream_t stream)
{
    (void)in_sizes; (void)n_in; (void)out_size;
    const float* x  = (const float*)d_in[0];
    const float* W1 = (const float*)d_in[1];
    const float* b1 = (const float*)d_in[2];
    const float* W2 = (const float*)d_in[3];
    const float* b2 = (const float*)d_in[4];
    const float* Wx = (const float*)d_in[5];
    const float* Wh = (const float*)d_in[6];
    const float* bl = (const float*)d_in[7];
    const float* W3 = (const float*)d_in[8];
    const float* b3 = (const float*)d_in[9];
    const float* W4 = (const float*)d_in[10];
    const float* b4 = (const float*)d_in[11];
    float* out = (float*)d_out;

    const size_t hsElems = (size_t)128 * 1024 * 32;    // 16 MB
    const size_t xgElems = (size_t)128 * 1024 * 128;   // 64 MB
    float* hs = (float*)d_ws;
    float* xg = (ws_size >= (hsElems + xgElems) * sizeof(float))
                    ? hs + hsElems
                    : out;   // stash xg in d_out; k3 rewrites d_out only after hs is done

    k_mlp_xg<<<2048, 256, 0, stream>>>(x, W1, b1, W2, b2, Wx, bl, xg);
    k_lstm<<<128, 64, 0, stream>>>(xg, Wh, hs);
    k_tail<<<2048, 256, 0, stream>>>(hs, W3, b3, W4, b4, out);
}